// Round 4
// baseline (365.015 us; speedup 1.0000x reference)
//
#include <hip/hip_runtime.h>
#include <math.h>

// SphericalExpansion round 4: counting-sort with PAYLOAD materialization.
//   1. k_hist:    rid = z[idx_j] + 4*idx_i; rid_arr; histogram (L2-resident)
//   2. scan1/2/3: exclusive scan of counts -> cursor
//   3. k_scatter: pos = cursor[rid]++; payload[pos] = (x,y,z,r)   <- data, not id
//   4. k_gather:  one wave per row; sequential uniform float4 payload reads;
//                 Ylm coefficients pinned in VGPRs (volatile loads); single
//                 coalesced 128-float row write (no out memset needed).
// cursor after scatter == row end offsets, so gather needs no separate offsets.

#define NSPEC 4

// Monomial order (20): 1, x, y, z, xx, yy, zz, xy, xz, yz,
//                      xxx, xxy, xxz, xyy, xyz, xzz, yyy, yyz, yzz, zzz
__constant__ float YCOEF[16 * 20] = {
    0.28209479177387814f,0,0,0, 0,0,0,0, 0,0, 0,0,0,0, 0,0,0,0, 0,0,
    0,0,0.4886025119029199f,0, 0,0,0,0, 0,0, 0,0,0,0, 0,0,0,0, 0,0,
    0,0,0,0.4886025119029199f, 0,0,0,0, 0,0, 0,0,0,0, 0,0,0,0, 0,0,
    0,0.4886025119029199f,0,0, 0,0,0,0, 0,0, 0,0,0,0, 0,0,0,0, 0,0,
    0,0,0,0, 0,0,0,1.0925484305920792f, 0,0, 0,0,0,0, 0,0,0,0, 0,0,
    0,0,0,0, 0,0,0,0, 0,1.0925484305920792f, 0,0,0,0, 0,0,0,0, 0,0,
    0,0,0,0, -0.31539156525252005f,-0.31539156525252005f,0.6307831305050401f,0, 0,0, 0,0,0,0, 0,0,0,0, 0,0,
    0,0,0,0, 0,0,0,0, 1.0925484305920792f,0, 0,0,0,0, 0,0,0,0, 0,0,
    0,0,0,0, 0.5462742152960396f,-0.5462742152960396f,0,0, 0,0, 0,0,0,0, 0,0,0,0, 0,0,
    0,0,0,0, 0,0,0,0, 0,0, 0,1.7701307697799305f,0,0, 0,0,-0.5900435899266435f,0, 0,0,
    0,0,0,0, 0,0,0,0, 0,0, 0,0,0,0, 2.890611442640554f,0,0,0, 0,0,
    0,0,0,0, 0,0,0,0, 0,0, 0,-0.4570457994644658f,0,0, 0,0,-0.4570457994644658f,0, 1.8281831978578632f,0,
    0,0,0,0, 0,0,0,0, 0,0, 0,0,-1.1195289977703462f,0, 0,0,0,-1.1195289977703462f, 0,0.7463526651802308f,
    0,0,0,0, 0,0,0,0, 0,0, -0.4570457994644658f,0,0,-0.4570457994644658f, 0,1.8281831978578632f,0,0, 0,0,
    0,0,0,0, 0,0,0,0, 0,0, 0,0,1.445305721320277f,0, 0,0,0,-1.445305721320277f, 0,0,
    0,0,0,0, 0,0,0,0, 0,0, 0.5900435899266435f,0,0,-1.7701307697799305f, 0,0,0,0, 0,0,
};

__global__ __launch_bounds__(256) void k_hist(
    const int* __restrict__ zsp, const int* __restrict__ idx_i,
    const int* __restrict__ idx_j, int* __restrict__ rid_arr,
    int* __restrict__ counts, int J)
{
    int e = blockIdx.x * 256 + threadIdx.x;
    if (e >= J) return;
    int rid = zsp[idx_j[e]] + NSPEC * idx_i[e];
    rid_arr[e] = rid;
    atomicAdd(&counts[rid], 1);
}

__global__ __launch_bounds__(256) void k_scan1(
    const int* __restrict__ counts, int* __restrict__ cursor,
    int* __restrict__ bsums, int n)
{
    __shared__ int s[256];
    int i = blockIdx.x * 256 + threadIdx.x;
    int v = (i < n) ? counts[i] : 0;
    s[threadIdx.x] = v;
    __syncthreads();
    for (int off = 1; off < 256; off <<= 1) {
        int t = (threadIdx.x >= off) ? s[threadIdx.x - off] : 0;
        __syncthreads();
        s[threadIdx.x] += t;
        __syncthreads();
    }
    if (i < n) cursor[i] = s[threadIdx.x] - v;     // block-local exclusive
    if (threadIdx.x == 255) bsums[blockIdx.x] = s[255];
}

__global__ __launch_bounds__(512) void k_scan2(int* __restrict__ bsums, int nb)
{
    __shared__ int s[512];
    int t = threadIdx.x;
    int v = (t < nb) ? bsums[t] : 0;
    s[t] = v;
    __syncthreads();
    for (int off = 1; off < 512; off <<= 1) {
        int u = (t >= off) ? s[t - off] : 0;
        __syncthreads();
        s[t] += u;
        __syncthreads();
    }
    if (t < nb) bsums[t] = s[t] - v;               // exclusive
}

__global__ __launch_bounds__(256) void k_scan3(
    int* __restrict__ cursor, const int* __restrict__ bsums, int n)
{
    int i = blockIdx.x * 256 + threadIdx.x;
    if (i < n) cursor[i] += bsums[blockIdx.x];
}

__global__ __launch_bounds__(256) void k_scatter(
    const float* __restrict__ dist, const float* __restrict__ dirs,
    const int* __restrict__ rid_arr, int* __restrict__ cursor,
    float4* __restrict__ payload, int J)
{
    int e = blockIdx.x * 256 + threadIdx.x;
    if (e >= J) return;
    int pos = atomicAdd(&cursor[rid_arr[e]], 1);
    float4 v;
    v.x = dirs[3 * e + 0];
    v.y = dirs[3 * e + 1];
    v.z = dirs[3 * e + 2];
    v.w = dist[e];
    payload[pos] = v;
}

// One 64-lane wave per row. lane: lm = lane&15, n in {lane>>4, lane>>4 + 4}.
// ends[] = cursor after scatter (row r spans [ends[r-1], ends[r])).
__global__ __launch_bounds__(256) void k_gather(
    const float4* __restrict__ payload,
    const float*  __restrict__ centers,
    const int*    __restrict__ ends,
    float* __restrict__ out, int nrows)
{
    int wid  = (blockIdx.x * 256 + threadIdx.x) >> 6;
    int lane = threadIdx.x & 63;
    int row  = __builtin_amdgcn_readfirstlane(wid);
    if (row >= nrows) return;

    int lm = lane & 15;
    int np = lane >> 4;
    int l  = (lm >= 9) ? 3 : (lm >= 4) ? 2 : (lm >= 1) ? 1 : 0;
    float cen0 = centers[l * 8 + np];
    float cen1 = centers[l * 8 + np + 4];

    // volatile: forces the 20 coefficients to stay resident in VGPRs across
    // the loop (round-3 had VGPR_Count=24 -> compiler reloaded them per edge)
    volatile const float* cr = &YCOEF[lm * 20];
    float k0 = cr[0],  k1 = cr[1],  k2 = cr[2],  k3 = cr[3],  k4 = cr[4];
    float k5 = cr[5],  k6 = cr[6],  k7 = cr[7],  k8 = cr[8],  k9 = cr[9];
    float k10 = cr[10], k11 = cr[11], k12 = cr[12], k13 = cr[13], k14 = cr[14];
    float k15 = cr[15], k16 = cr[16], k17 = cr[17], k18 = cr[18], k19 = cr[19];

    int beg = (row == 0) ? 0 : ends[row - 1];
    int end = ends[row];
    beg = __builtin_amdgcn_readfirstlane(beg);
    end = __builtin_amdgcn_readfirstlane(end);

    float a0 = 0.0f, a1 = 0.0f;
    for (int i = beg; i < end; ++i) {
        float4 P = payload[i];          // uniform sequential -> scalar-cache
        float x = P.x, y = P.y, z = P.z, r = P.w;

        float xx = x*x, yy = y*y, zz = z*z;
        float xy = x*y, xz = x*z, yz = y*z;
        // 4 independent partial sums: short fma chains
        float s0 = fmaf(k1, x,  fmaf(k2, y,  fmaf(k3, z, k0)));
        float s1 = fmaf(k4, xx, fmaf(k5, yy, fmaf(k6, zz, k7*xy)));
        float s2 = fmaf(k8, xz, fmaf(k9, yz, fmaf(k10, xx*x, k11*(xx*y))));
        float s3 = fmaf(k12, xx*z, fmaf(k13, x*yy, fmaf(k14, xy*z, k15*(x*zz))));
        float s4 = fmaf(k16, yy*y, fmaf(k17, yy*z, fmaf(k18, y*zz, k19*(zz*z))));
        float ylm = (s0 + s1) + (s2 + s3) + s4;

        float u  = fminf(fmaxf((r - 4.5f) * 2.0f, 0.0f), 1.0f);
        float fc = fmaf(0.5f, __cosf(3.14159265358979f * u), 0.5f);
        float p  = fc * ylm;

        float d0 = (r - cen0) * 2.0f;
        float d1 = (r - cen1) * 2.0f;
        a0 = fmaf(p, __expf(-0.5f * d0 * d0), a0);
        a1 = fmaf(p, __expf(-0.5f * d1 * d1), a1);
    }

    size_t base = (size_t)row * 128;
    out[base + lane]      = a0;   // np*16 + lm == lane
    out[base + lane + 64] = a1;   // (np+4)*16 + lm == lane + 64
}

// Fallback (round-2 atomic scatter) if workspace is too small.
__global__ __launch_bounds__(256) void sphexp16_fb(
    const float* __restrict__ dist, const float* __restrict__ dirs,
    const float* __restrict__ centers, const int* __restrict__ zsp,
    const int* __restrict__ idx_i, const int* __restrict__ idx_j,
    float* __restrict__ out, int J)
{
    int tid = blockIdx.x * 256 + threadIdx.x;
    int e = tid >> 4, t = tid & 15;
    if (e >= J) return;
    float r = dist[e];
    float x = dirs[3*e], y = dirs[3*e+1], z = dirs[3*e+2];
    int rid = zsp[idx_j[e]] + NSPEC * idx_i[e];
    size_t base = (size_t)rid * 128 + t;
    const float* cr = &YCOEF[t * 20];
    float xx=x*x, yy=y*y, zz=z*z;
    float ylm = cr[0] + cr[1]*x + cr[2]*y + cr[3]*z
              + cr[4]*xx + cr[5]*yy + cr[6]*zz + cr[7]*(x*y)
              + cr[8]*(x*z) + cr[9]*(y*z)
              + cr[10]*(xx*x) + cr[11]*(xx*y) + cr[12]*(xx*z)
              + cr[13]*(x*yy) + cr[14]*(x*y*z) + cr[15]*(x*zz)
              + cr[16]*(yy*y) + cr[17]*(yy*z) + cr[18]*(y*zz) + cr[19]*(zz*z);
    float u = fminf(fmaxf((r - 4.5f) * 2.0f, 0.0f), 1.0f);
    float fc = 0.5f * (1.0f + __cosf(3.14159265358979f * u));
    int l = (t >= 9) ? 3 : (t >= 4) ? 2 : (t >= 1) ? 1 : 0;
    float pref = fc * ylm;
#pragma unroll
    for (int n = 0; n < 8; n++) {
        float d = (r - centers[l*8+n]) * 2.0f;
        atomicAdd(out + base + (size_t)(n*16), pref * __expf(-0.5f*d*d));
    }
}

extern "C" void kernel_launch(void* const* d_in, const int* in_sizes, int n_in,
                              void* d_out, int out_size, void* d_ws, size_t ws_size,
                              hipStream_t stream) {
    const float* dist    = (const float*)d_in[0];
    const float* dirs    = (const float*)d_in[1];
    const float* centers = (const float*)d_in[2];
    const int*   zsp     = (const int*)d_in[3];
    const int*   idx_i   = (const int*)d_in[4];
    const int*   idx_j   = (const int*)d_in[5];
    float* out = (float*)d_out;

    int J      = in_sizes[0];
    int natoms = in_sizes[3];
    int nrows  = natoms * NSPEC;

    // ws layout: payload [J float4] | rid_arr [J] | counts [nrows] | cursor [nrows] | bsums [512]
    size_t need = (size_t)J * 16 + ((size_t)J + 2 * (size_t)nrows + 512) * 4;
    if (ws_size < need) {
        hipMemsetAsync(d_out, 0, (size_t)out_size * sizeof(float), stream);
        long long total = (long long)J * 16;
        sphexp16_fb<<<(int)((total + 255) / 256), 256, 0, stream>>>(
            dist, dirs, centers, zsp, idx_i, idx_j, out, J);
        return;
    }

    float4* payload = (float4*)d_ws;
    int* rid_arr = (int*)(payload + J);
    int* counts  = rid_arr + J;
    int* cursor  = counts + nrows;
    int* bsums   = cursor + nrows;

    int nb1 = (nrows + 255) / 256;     // 313 for nrows=80000 (<= 512)

    hipMemsetAsync(counts, 0, (size_t)nrows * sizeof(int), stream);
    k_hist<<<(J + 255) / 256, 256, 0, stream>>>(zsp, idx_i, idx_j, rid_arr, counts, J);
    k_scan1<<<nb1, 256, 0, stream>>>(counts, cursor, bsums, nrows);
    k_scan2<<<1, 512, 0, stream>>>(bsums, nb1);
    k_scan3<<<nb1, 256, 0, stream>>>(cursor, bsums, nrows);
    k_scatter<<<(J + 255) / 256, 256, 0, stream>>>(dist, dirs, rid_arr, cursor, payload, J);
    k_gather<<<(int)(((size_t)nrows * 64 + 255) / 256), 256, 0, stream>>>(
        payload, centers, cursor, out, nrows);
}

// Round 5
// 223.884 us; speedup vs baseline: 1.6304x; 1.6304x over previous
//
#include <hip/hip_runtime.h>
#include <math.h>

// SphericalExpansion round 5: counting-sort (payload) + Design-D gather.
//   1. memset counts
//   2. k_hist:    rid = z[idx_j] + 4*idx_i -> rid_arr, histogram counts
//   3. k_scan1:   per-256-block exclusive scan -> cursor, block sums -> bsums
//   4. k_scan2:   exclusive scan of bsums (single block)
//   5. k_scatter: pos = bsums[rid>>8] + cursor[rid]++ ; payload[pos]=(x,y,z,r)
//   6. k_gather:  4 rows/wave, 16 lanes/row (lane owns lm, 8 n-accumulators in
//                 registers). Ylm coeffs + centers read from LDS per edge
//                 (broadcast-dedup, deterministic — avoids the round-3/4
//                 register-remat pathology). Single coalesced row write.
// Row bounds in gather: end(r) = bsums[r>>8] + cursor[r]  (cursor is local
// inclusive after scatter), beg(r) = end(r-1). No k_scan3 needed.

#define NSPEC 4

// Monomial order (20): 1, x, y, z | xx, yy, zz, xy | xz, yz, xxx, xxy |
//                      xxz, xyy, xyz, xzz | yyy, yyz, yzz, zzz
__constant__ float YCOEF[16 * 20] = {
    0.28209479177387814f,0,0,0, 0,0,0,0, 0,0,0,0, 0,0,0,0, 0,0,0,0,
    0,0,0.4886025119029199f,0, 0,0,0,0, 0,0,0,0, 0,0,0,0, 0,0,0,0,
    0,0,0,0.4886025119029199f, 0,0,0,0, 0,0,0,0, 0,0,0,0, 0,0,0,0,
    0,0.4886025119029199f,0,0, 0,0,0,0, 0,0,0,0, 0,0,0,0, 0,0,0,0,
    0,0,0,0, 0,0,0,1.0925484305920792f, 0,0,0,0, 0,0,0,0, 0,0,0,0,
    0,0,0,0, 0,0,0,0, 0,1.0925484305920792f,0,0, 0,0,0,0, 0,0,0,0,
    0,0,0,0, -0.31539156525252005f,-0.31539156525252005f,0.6307831305050401f,0, 0,0,0,0, 0,0,0,0, 0,0,0,0,
    0,0,0,0, 0,0,0,0, 1.0925484305920792f,0,0,0, 0,0,0,0, 0,0,0,0,
    0,0,0,0, 0.5462742152960396f,-0.5462742152960396f,0,0, 0,0,0,0, 0,0,0,0, 0,0,0,0,
    0,0,0,0, 0,0,0,0, 0,0,0,1.7701307697799305f, 0,0,0,0, -0.5900435899266435f,0,0,0,
    0,0,0,0, 0,0,0,0, 0,0,0,0, 0,0,2.890611442640554f,0, 0,0,0,0,
    0,0,0,0, 0,0,0,0, 0,0,0,-0.4570457994644658f, 0,0,0,0, -0.4570457994644658f,0,1.8281831978578632f,0,
    0,0,0,0, 0,0,0,0, 0,0,0,0, -1.1195289977703462f,0,0,0, 0,-1.1195289977703462f,0,0.7463526651802308f,
    0,0,0,0, 0,0,0,0, 0,0,-0.4570457994644658f,0, 0,-0.4570457994644658f,0,1.8281831978578632f, 0,0,0,0,
    0,0,0,0, 0,0,0,0, 0,0,0,0, 1.445305721320277f,0,0,0, 0,-1.445305721320277f,0,0,
    0,0,0,0, 0,0,0,0, 0,0,0.5900435899266435f,0, 0,-1.7701307697799305f,0,0, 0,0,0,0,
};

__global__ __launch_bounds__(256) void k_hist(
    const int* __restrict__ zsp, const int* __restrict__ idx_i,
    const int* __restrict__ idx_j, int* __restrict__ rid_arr,
    int* __restrict__ counts, int J)
{
    int e = blockIdx.x * 256 + threadIdx.x;
    if (e >= J) return;
    int rid = zsp[idx_j[e]] + NSPEC * idx_i[e];
    rid_arr[e] = rid;
    atomicAdd(&counts[rid], 1);
}

__global__ __launch_bounds__(256) void k_scan1(
    const int* __restrict__ counts, int* __restrict__ cursor,
    int* __restrict__ bsums, int n)
{
    __shared__ int s[256];
    int i = blockIdx.x * 256 + threadIdx.x;
    int v = (i < n) ? counts[i] : 0;
    s[threadIdx.x] = v;
    __syncthreads();
    for (int off = 1; off < 256; off <<= 1) {
        int t = (threadIdx.x >= off) ? s[threadIdx.x - off] : 0;
        __syncthreads();
        s[threadIdx.x] += t;
        __syncthreads();
    }
    if (i < n) cursor[i] = s[threadIdx.x] - v;     // block-local exclusive
    if (threadIdx.x == 255) bsums[blockIdx.x] = s[255];
}

__global__ __launch_bounds__(512) void k_scan2(int* __restrict__ bsums, int nb)
{
    __shared__ int s[512];
    int t = threadIdx.x;
    int v = (t < nb) ? bsums[t] : 0;
    s[t] = v;
    __syncthreads();
    for (int off = 1; off < 512; off <<= 1) {
        int u = (t >= off) ? s[t - off] : 0;
        __syncthreads();
        s[t] += u;
        __syncthreads();
    }
    if (t < nb) bsums[t] = s[t] - v;               // exclusive
}

__global__ __launch_bounds__(256) void k_scatter(
    const float* __restrict__ dist, const float* __restrict__ dirs,
    const int* __restrict__ rid_arr, int* __restrict__ cursor,
    const int* __restrict__ bsums,
    float4* __restrict__ payload, int J)
{
    int e = blockIdx.x * 256 + threadIdx.x;
    if (e >= J) return;
    int rid = rid_arr[e];
    int pos = bsums[rid >> 8] + atomicAdd(&cursor[rid], 1);
    float4 v;
    v.x = dirs[3 * e + 0];
    v.y = dirs[3 * e + 1];
    v.z = dirs[3 * e + 2];
    v.w = dist[e];
    payload[pos] = v;
}

// Design-D gather: block=256 -> 4 waves -> 16 rows/block.
// Lane: q = lane>>4 (row in wave), t = lane&15 (lm). 8 n-accumulators/lane.
__global__ __launch_bounds__(256) void k_gather(
    const float4* __restrict__ payload,
    const float*  __restrict__ centers,
    const int*    __restrict__ cursor,   // local INCLUSIVE prefix after scatter
    const int*    __restrict__ bsums,    // exclusive block sums
    float* __restrict__ out, int nrows)
{
    __shared__ float sC[16 * 20];
    __shared__ float sCen[32];
    for (int i = threadIdx.x; i < 352; i += 256) {
        if (i < 320) sC[i] = YCOEF[i];
        else         sCen[i - 320] = centers[i - 320];
    }
    __syncthreads();

    int wave = threadIdx.x >> 6;
    int lane = threadIdx.x & 63;
    int q = lane >> 4;
    int t = lane & 15;
    int row = blockIdx.x * 16 + wave * 4 + q;
    if (row >= nrows) return;

    int l = (t >= 9) ? 3 : (t >= 4) ? 2 : (t >= 1) ? 1 : 0;

    int end = bsums[row >> 8] + cursor[row];
    int beg = (row == 0) ? 0 : bsums[(row - 1) >> 8] + cursor[row - 1];

    const float4* cr = (const float4*)(&sC[t * 20]);   // 20 coefs = 5 x float4
    const float4* cn = (const float4*)(&sCen[l * 8]);  // 8 centers = 2 x float4

    float a0 = 0, a1 = 0, a2 = 0, a3 = 0, a4 = 0, a5 = 0, a6 = 0, a7 = 0;

    for (int i = beg; i < end; ++i) {
        float4 P = payload[i];                  // uniform per 16-lane group
        float x = P.x, y = P.y, z = P.z, r = P.w;

        // coefs re-read from LDS every edge: deterministic, broadcast-dedup
        float4 c0 = cr[0], c1 = cr[1], c2 = cr[2], c3 = cr[3], c4 = cr[4];
        float xx = x * x, yy = y * y, zz = z * z;
        float s0 = fmaf(c0.y, x,      fmaf(c0.z, y,      fmaf(c0.w, z,      c0.x)));
        float s1 = fmaf(c1.x, xx,     fmaf(c1.y, yy,     fmaf(c1.z, zz,     c1.w * (x*y))));
        float s2 = fmaf(c2.x, x*z,    fmaf(c2.y, y*z,    fmaf(c2.z, xx*x,   c2.w * (xx*y))));
        float s3 = fmaf(c3.x, xx*z,   fmaf(c3.y, x*yy,   fmaf(c3.z, x*y*z,  c3.w * (x*zz))));
        float s4 = fmaf(c4.x, yy*y,   fmaf(c4.y, yy*z,   fmaf(c4.z, y*zz,   c4.w * (zz*z))));
        float ylm = (s0 + s1) + (s2 + s3) + s4;

        float u  = fminf(fmaxf((r - 4.5f) * 2.0f, 0.0f), 1.0f);
        float fc = fmaf(0.5f, __cosf(3.14159265358979f * u), 0.5f);
        float p  = fc * ylm;

        float4 cA = cn[0], cB = cn[1];
        float d;
        d = r - cA.x; a0 = fmaf(p, __expf(-2.0f * d * d), a0);
        d = r - cA.y; a1 = fmaf(p, __expf(-2.0f * d * d), a1);
        d = r - cA.z; a2 = fmaf(p, __expf(-2.0f * d * d), a2);
        d = r - cA.w; a3 = fmaf(p, __expf(-2.0f * d * d), a3);
        d = r - cB.x; a4 = fmaf(p, __expf(-2.0f * d * d), a4);
        d = r - cB.y; a5 = fmaf(p, __expf(-2.0f * d * d), a5);
        d = r - cB.z; a6 = fmaf(p, __expf(-2.0f * d * d), a6);
        d = r - cB.w; a7 = fmaf(p, __expf(-2.0f * d * d), a7);
    }

    float* o = out + (size_t)row * 128 + t;     // slot = n*16 + t
    o[0]   = a0; o[16]  = a1; o[32]  = a2; o[48]  = a3;
    o[64]  = a4; o[80]  = a5; o[96]  = a6; o[112] = a7;
}

// Fallback (round-2 atomic scatter) if workspace too small / scan won't fit.
__global__ __launch_bounds__(256) void sphexp16_fb(
    const float* __restrict__ dist, const float* __restrict__ dirs,
    const float* __restrict__ centers, const int* __restrict__ zsp,
    const int* __restrict__ idx_i, const int* __restrict__ idx_j,
    float* __restrict__ out, int J)
{
    int tid = blockIdx.x * 256 + threadIdx.x;
    int e = tid >> 4, t = tid & 15;
    if (e >= J) return;
    float r = dist[e];
    float x = dirs[3*e], y = dirs[3*e+1], z = dirs[3*e+2];
    int rid = zsp[idx_j[e]] + NSPEC * idx_i[e];
    size_t base = (size_t)rid * 128 + t;
    const float* cr = &YCOEF[t * 20];
    float xx=x*x, yy=y*y, zz=z*z;
    float ylm = cr[0] + cr[1]*x + cr[2]*y + cr[3]*z
              + cr[4]*xx + cr[5]*yy + cr[6]*zz + cr[7]*(x*y)
              + cr[8]*(x*z) + cr[9]*(y*z)
              + cr[10]*(xx*x) + cr[11]*(xx*y) + cr[12]*(xx*z)
              + cr[13]*(x*yy) + cr[14]*(x*y*z) + cr[15]*(x*zz)
              + cr[16]*(yy*y) + cr[17]*(yy*z) + cr[18]*(y*zz) + cr[19]*(zz*z);
    float u = fminf(fmaxf((r - 4.5f) * 2.0f, 0.0f), 1.0f);
    float fc = 0.5f * (1.0f + __cosf(3.14159265358979f * u));
    int l = (t >= 9) ? 3 : (t >= 4) ? 2 : (t >= 1) ? 1 : 0;
    float pref = fc * ylm;
#pragma unroll
    for (int n = 0; n < 8; n++) {
        float d = r - centers[l*8+n];
        atomicAdd(out + base + (size_t)(n*16), pref * __expf(-2.0f*d*d));
    }
}

extern "C" void kernel_launch(void* const* d_in, const int* in_sizes, int n_in,
                              void* d_out, int out_size, void* d_ws, size_t ws_size,
                              hipStream_t stream) {
    const float* dist    = (const float*)d_in[0];
    const float* dirs    = (const float*)d_in[1];
    const float* centers = (const float*)d_in[2];
    const int*   zsp     = (const int*)d_in[3];
    const int*   idx_i   = (const int*)d_in[4];
    const int*   idx_j   = (const int*)d_in[5];
    float* out = (float*)d_out;

    int J      = in_sizes[0];
    int natoms = in_sizes[3];
    int nrows  = natoms * NSPEC;
    int nb1    = (nrows + 255) / 256;

    // ws layout: payload [J float4] | rid_arr [J] | counts [nrows] | cursor [nrows] | bsums [512]
    size_t need = (size_t)J * 16 + ((size_t)J + 2 * (size_t)nrows + 512) * 4;
    if (ws_size < need || nb1 > 512) {
        hipMemsetAsync(d_out, 0, (size_t)out_size * sizeof(float), stream);
        long long total = (long long)J * 16;
        sphexp16_fb<<<(int)((total + 255) / 256), 256, 0, stream>>>(
            dist, dirs, centers, zsp, idx_i, idx_j, out, J);
        return;
    }

    float4* payload = (float4*)d_ws;
    int* rid_arr = (int*)(payload + J);
    int* counts  = rid_arr + J;
    int* cursor  = counts + nrows;
    int* bsums   = cursor + nrows;

    hipMemsetAsync(counts, 0, (size_t)nrows * sizeof(int), stream);
    k_hist<<<(J + 255) / 256, 256, 0, stream>>>(zsp, idx_i, idx_j, rid_arr, counts, J);
    k_scan1<<<nb1, 256, 0, stream>>>(counts, cursor, bsums, nrows);
    k_scan2<<<1, 512, 0, stream>>>(bsums, nb1);
    k_scatter<<<(J + 255) / 256, 256, 0, stream>>>(
        dist, dirs, rid_arr, cursor, bsums, payload, J);
    k_gather<<<(nrows + 15) / 16, 256, 0, stream>>>(
        payload, centers, cursor, bsums, out, nrows);
}